// Round 9
// baseline (36.195 us; speedup 1.0000x reference)
//
#include <hip/hip_runtime.h>
#include <hip/hip_fp16.h>

#define D 300
#define NS 256
#define NA 256
#define W 8
#define NROWS 2048    // 256*8
#define NCHUNK 10     // K padded to 10 chunks of 32 (320)

typedef _Float16 half8 __attribute__((ext_vector_type(8)));
typedef float f32x4 __attribute__((ext_vector_type(4)));

// Swizzled operand layout (halves): [rt(128)][c(10)][lane(64)][e(8)]
// lane = lk*16 + lr, where row = rt*16+lr, k = c*32 + lk*8 + e.
__device__ __forceinline__ int swaddr(int rt, int lr, int k4) {
    int c = k4 >> 5, lk = (k4 & 31) >> 3, e = k4 & 7;   // e in {0,4}
    return ((rt * NCHUNK + c) * 64 + lk * 16 + lr) * 8 + e;
}

__device__ __forceinline__ void split4(float4 v, ushort4& h, ushort4& l) {
    float xs[4] = {v.x, v.y, v.z, v.w};
    unsigned short* hp = &h.x;
    unsigned short* lp = &l.x;
#pragma unroll
    for (int j = 0; j < 4; ++j) {
        __half hh = __float2half(xs[j]);
        float hf = __half2float(hh);
        __half ll = __float2half(xs[j] - hf);
        hp[j] = __half_as_ushort(hh);
        lp[j] = __half_as_ushort(ll);
    }
}

// ---- gather: one wave per task (256 sen categories + 2048 ann rows) ----
__global__ __launch_bounds__(256) void k_gather(const float* __restrict__ emb,
                                                const int* __restrict__ sen_cats,
                                                const int* __restrict__ ann_cats,
                                                const int* __restrict__ none_idx,
                                                unsigned short* __restrict__ AHI,
                                                unsigned short* __restrict__ ALO,
                                                unsigned short* __restrict__ BHI,
                                                unsigned short* __restrict__ BLO,
                                                float* __restrict__ rsn,
                                                float* __restrict__ ran,
                                                int* __restrict__ sflag,
                                                float* __restrict__ out2) {
    int tid = threadIdx.x;
    int wv = tid >> 6, lane = tid & 63;
    int task = blockIdx.x * 4 + wv;

    if (task < NS) {
        int b = task;
        bool has2 = (lane + 64) < 75;            // lane < 11
        float4 sum0 = make_float4(0.f, 0.f, 0.f, 0.f);
        float4 sum1 = make_float4(0.f, 0.f, 0.f, 0.f);
        int nidx = none_idx[0];
        for (int w = 0; w < W; ++w) {
            int r = b * W + w;
            int cat = sen_cats[r];
            const float4* src = reinterpret_cast<const float4*>(emb + (size_t)cat * D);
            int rt = r >> 4, lr = r & 15;
            float4 v0 = src[lane];
            ushort4 h0, l0;
            split4(v0, h0, l0);
            int a0 = swaddr(rt, lr, lane * 4);
            *reinterpret_cast<ushort4*>(AHI + a0) = h0;
            *reinterpret_cast<ushort4*>(ALO + a0) = l0;
            double acc = (double)v0.x * v0.x + (double)v0.y * v0.y +
                         (double)v0.z * v0.z + (double)v0.w * v0.w;
            sum0.x += v0.x; sum0.y += v0.y; sum0.z += v0.z; sum0.w += v0.w;
            if (has2) {
                float4 v1 = src[lane + 64];
                ushort4 h1, l1;
                split4(v1, h1, l1);
                int a1 = swaddr(rt, lr, (lane + 64) * 4);
                *reinterpret_cast<ushort4*>(AHI + a1) = h1;
                *reinterpret_cast<ushort4*>(ALO + a1) = l1;
                acc += (double)v1.x * v1.x + (double)v1.y * v1.y +
                       (double)v1.z * v1.z + (double)v1.w * v1.w;
                sum1.x += v1.x; sum1.y += v1.y; sum1.z += v1.z; sum1.w += v1.w;
            } else if (lane < 16) {
                // zero K-pad: k = 300..319 (lanes 11..15)
                ushort4 z = {0, 0, 0, 0};
                int a1 = swaddr(rt, lr, (lane + 64) * 4);
                *reinterpret_cast<ushort4*>(AHI + a1) = z;
                *reinterpret_cast<ushort4*>(ALO + a1) = z;
            }
            for (int off = 32; off > 0; off >>= 1) acc += __shfl_down(acc, off, 64);
            if (lane == 0) {
                rsn[r] = (float)(1.0 / sqrt(acc));   // norms ~17, eps unreachable
                sflag[r] = (cat == nidx) ? 1 : 0;
            }
        }
        float4* o = reinterpret_cast<float4*>(out2 + (size_t)b * D);
        o[lane] = sum0;
        if (has2) o[lane + 64] = sum1;
    } else {
        int r = task - NS;   // ann row
        int cat = ann_cats[r];
        const float4* src = reinterpret_cast<const float4*>(emb + (size_t)cat * D);
        int rt = r >> 4, lr = r & 15;
        float4 v0 = src[lane];
        ushort4 h0, l0;
        split4(v0, h0, l0);
        int a0 = swaddr(rt, lr, lane * 4);
        *reinterpret_cast<ushort4*>(BHI + a0) = h0;
        *reinterpret_cast<ushort4*>(BLO + a0) = l0;
        double acc = (double)v0.x * v0.x + (double)v0.y * v0.y +
                     (double)v0.z * v0.z + (double)v0.w * v0.w;
        if (lane < 11) {
            float4 v1 = src[lane + 64];
            ushort4 h1, l1;
            split4(v1, h1, l1);
            int a1 = swaddr(rt, lr, (lane + 64) * 4);
            *reinterpret_cast<ushort4*>(BHI + a1) = h1;
            *reinterpret_cast<ushort4*>(BLO + a1) = l1;
            acc += (double)v1.x * v1.x + (double)v1.y * v1.y +
                   (double)v1.z * v1.z + (double)v1.w * v1.w;
        } else if (lane < 16) {
            ushort4 z = {0, 0, 0, 0};
            int a1 = swaddr(rt, lr, (lane + 64) * 4);
            *reinterpret_cast<ushort4*>(BHI + a1) = z;
            *reinterpret_cast<ushort4*>(BLO + a1) = z;
        }
        for (int off = 32; off > 0; off >>= 1) acc += __shfl_down(acc, off, 64);
        if (lane == 0) ran[r] = (float)(1.0 / sqrt(acc));
    }
}

// ---- main: 8 waves (2/SIMD), wave tile 64x32, pass-major MFMA, ping-pong loads ----
__global__ __launch_bounds__(512, 2) void k_main(const unsigned short* __restrict__ AHIu,
                                                 const unsigned short* __restrict__ ALOu,
                                                 const unsigned short* __restrict__ BHIu,
                                                 const unsigned short* __restrict__ BLOu,
                                                 const float* __restrict__ rsn,
                                                 const float* __restrict__ ran,
                                                 const int* __restrict__ sflag,
                                                 float* __restrict__ out) {
    const _Float16* AHI = reinterpret_cast<const _Float16*>(AHIu);
    const _Float16* ALO = reinterpret_cast<const _Float16*>(ALOu);
    const _Float16* BHI = reinterpret_cast<const _Float16*>(BHIu);
    const _Float16* BLO = reinterpret_cast<const _Float16*>(BLOu);

    __shared__ float cosld[128][128];   // 64 KB exactly

    int tid = threadIdx.x;
    int wv = tid >> 6, lane = tid & 63;
    int wy = wv >> 2, wx = wv & 3;      // wave tile: 64 rows x 32 cols
    int lr = lane & 15;
    int lk = lane >> 4;
    int by = blockIdx.y, bx = blockIdx.x;

    // swizzled bases: element ((rt*10 + c)*64 + lane)*8 ; chunk stride 512
    int aBase[4], bBase[2];
#pragma unroll
    for (int m = 0; m < 4; ++m)
        aBase[m] = (((by * 8 + wy * 4 + m) * NCHUNK) * 64 + lane) * 8;
#pragma unroll
    for (int n = 0; n < 2; ++n)
        bBase[n] = (((bx * 8 + wx * 2 + n) * NCHUNK) * 64 + lane) * 8;

    f32x4 acc[4][2] = {};
    // operand sets: [0..3]=A hi, [4..7]=A lo ; [0..1]=B hi, [2..3]=B lo
    half8 cA[8], cB[4], nA[8], nB[4];

    auto LOAD = [&](int c, half8* Av, half8* Bv) {
        int co = c * 512;
#pragma unroll
        for (int m = 0; m < 4; ++m) {
            Av[m] = *reinterpret_cast<const half8*>(AHI + aBase[m] + co);
            Av[m + 4] = *reinterpret_cast<const half8*>(ALO + aBase[m] + co);
        }
#pragma unroll
        for (int n = 0; n < 2; ++n) {
            Bv[n] = *reinterpret_cast<const half8*>(BHI + bBase[n] + co);
            Bv[n + 2] = *reinterpret_cast<const half8*>(BLO + bBase[n] + co);
        }
    };
    auto COMPUTE = [&](half8* Av, half8* Bv) {
        // pass-major: HH, HL, LH — 8 independent MFMAs between acc reuse;
        // per-acc order (HH,HL,LH per chunk) identical to r8 numerics.
#pragma unroll
        for (int m = 0; m < 4; ++m)
#pragma unroll
            for (int n = 0; n < 2; ++n)
                acc[m][n] = __builtin_amdgcn_mfma_f32_16x16x32_f16(Av[m], Bv[n], acc[m][n], 0, 0, 0);
#pragma unroll
        for (int m = 0; m < 4; ++m)
#pragma unroll
            for (int n = 0; n < 2; ++n)
                acc[m][n] = __builtin_amdgcn_mfma_f32_16x16x32_f16(Av[m], Bv[n + 2], acc[m][n], 0, 0, 0);
#pragma unroll
        for (int m = 0; m < 4; ++m)
#pragma unroll
            for (int n = 0; n < 2; ++n)
                acc[m][n] = __builtin_amdgcn_mfma_f32_16x16x32_f16(Av[m + 4], Bv[n], acc[m][n], 0, 0, 0);
    };

    LOAD(0, cA, cB);
#pragma unroll
    for (int c = 0; c < NCHUNK; c += 2) {
        LOAD(c + 1, nA, nB);            // NCHUNK even: c+1 always valid
        COMPUTE(cA, cB);
        if (c + 2 < NCHUNK) LOAD(c + 2, cA, cB);
        COMPUTE(nA, nB);
    }

    // epilogue: cosine scale (C/D: col=lane&15, row=(lane>>4)*4+reg) -> LDS
#pragma unroll
    for (int m = 0; m < 4; ++m) {
        int rbase = wy * 64 + m * 16 + lk * 4;
#pragma unroll
        for (int r = 0; r < 4; ++r) {
            int grow = by * 128 + rbase + r;
            float rsv = rsn[grow];
            float fm = sflag[grow] ? 0.f : 1.f;
            float rf = rsv * fm;
#pragma unroll
            for (int n = 0; n < 2; ++n) {
                int lc = wx * 32 + n * 16 + lr;
                float rav = ran[bx * 128 + lc];
                cosld[rbase + r][lc] = acc[m][n][r] * rf * rav;
            }
        }
    }
    __syncthreads();

    // order-dependent fold: one (s,a) pair per thread, w-major order
    if (tid < 256) {
        int pi = tid >> 4, pj = tid & 15;
        float cur = 0.f;
#pragma unroll
        for (int w = 0; w < W; ++w) {
            const float* rowp = &cosld[pi * 8 + w][pj * 8];
#pragma unroll
            for (int v = 0; v < W; ++v) {
                float sv = rowp[v];
                cur = (sv >= cur || sv < 0.f) ? sv : cur;
            }
        }
        out[(by * 16 + pi) * NA + (bx * 16 + pj)] = cur;
    }
}

extern "C" void kernel_launch(void* const* d_in, const int* in_sizes, int n_in,
                              void* d_out, int out_size, void* d_ws, size_t ws_size,
                              hipStream_t stream) {
    const float* emb = (const float*)d_in[0];
    const int* sen = (const int*)d_in[1];
    const int* ann = (const int*)d_in[2];
    const int* none = (const int*)d_in[3];
    float* out = (float*)d_out;

    char* ws = (char*)d_ws;
    unsigned short* AHI = (unsigned short*)(ws + 0);         // 2048*320*2 = 1,310,720
    unsigned short* ALO = (unsigned short*)(ws + 1310720);
    unsigned short* BHI = (unsigned short*)(ws + 2621440);
    unsigned short* BLO = (unsigned short*)(ws + 3932160);
    float* rsn = (float*)(ws + 5242880);                     // 8,192
    float* ran = (float*)(ws + 5251072);                     // 8,192
    int* sflag = (int*)(ws + 5259264);                       // 8,192

    hipLaunchKernelGGL(k_gather, dim3(576), dim3(256), 0, stream,
                       emb, sen, ann, none, AHI, ALO, BHI, BLO,
                       rsn, ran, sflag, out + NS * NA);
    hipLaunchKernelGGL(k_main, dim3(16, 16), dim3(512), 0, stream,
                       AHI, ALO, BHI, BLO, rsn, ran, sflag, out);
}

// Round 10
// 31.871 us; speedup vs baseline: 1.1357x; 1.1357x over previous
//
#include <hip/hip_runtime.h>
#include <hip/hip_fp16.h>

#define D 300
#define NS 256
#define NA 256
#define W 8
#define NROWS 2048    // 256*8
#define NCHUNK 10     // K padded to 10 chunks of 32 (320)

typedef _Float16 half8 __attribute__((ext_vector_type(8)));
typedef float f32x4 __attribute__((ext_vector_type(4)));

// Swizzled operand layout (halves): [rt(128)][c(10)][lane(64)][e(8)]
// lane = lk*16 + lr, where row = rt*16+lr, k = c*32 + lk*8 + e.
__device__ __forceinline__ int swaddr(int rt, int lr, int k4) {
    int c = k4 >> 5, lk = (k4 & 31) >> 3, e = k4 & 7;   // e in {0,4}
    return ((rt * NCHUNK + c) * 64 + lk * 16 + lr) * 8 + e;
}

__device__ __forceinline__ void split4(float4 v, ushort4& h, ushort4& l) {
    float xs[4] = {v.x, v.y, v.z, v.w};
    unsigned short* hp = &h.x;
    unsigned short* lp = &l.x;
#pragma unroll
    for (int j = 0; j < 4; ++j) {
        __half hh = __float2half(xs[j]);
        float hf = __half2float(hh);
        __half ll = __float2half(xs[j] - hf);
        hp[j] = __half_as_ushort(hh);
        lp[j] = __half_as_ushort(ll);
    }
}

// ---- gather: ONE WAVE PER ROW, fully parallel (4096 waves) ----
__global__ __launch_bounds__(256) void k_gather(const float* __restrict__ emb,
                                                const int* __restrict__ sen_cats,
                                                const int* __restrict__ ann_cats,
                                                const int* __restrict__ none_idx,
                                                unsigned short* __restrict__ AHI,
                                                unsigned short* __restrict__ ALO,
                                                unsigned short* __restrict__ BHI,
                                                unsigned short* __restrict__ BLO,
                                                float* __restrict__ rsn,
                                                float* __restrict__ ran,
                                                int* __restrict__ sflag) {
    int tid = threadIdx.x;
    int wv = tid >> 6, lane = tid & 63;
    int task = blockIdx.x * 4 + wv;
    bool isSen = task < NROWS;
    int r = isSen ? task : task - NROWS;
    int cat = isSen ? sen_cats[r] : ann_cats[r];
    unsigned short* HI = isSen ? AHI : BHI;
    unsigned short* LO = isSen ? ALO : BLO;
    int rt = r >> 4, lr = r & 15;

    const float4* src = reinterpret_cast<const float4*>(emb + (size_t)cat * D);
    float4 v0 = src[lane];                 // indices 0..63 of 75
    ushort4 h0, l0;
    split4(v0, h0, l0);
    int a0 = swaddr(rt, lr, lane * 4);
    *reinterpret_cast<ushort4*>(HI + a0) = h0;
    *reinterpret_cast<ushort4*>(LO + a0) = l0;
    double acc = (double)v0.x * v0.x + (double)v0.y * v0.y +
                 (double)v0.z * v0.z + (double)v0.w * v0.w;
    if (lane < 11) {                       // indices 64..74
        float4 v1 = src[lane + 64];
        ushort4 h1, l1;
        split4(v1, h1, l1);
        int a1 = swaddr(rt, lr, (lane + 64) * 4);
        *reinterpret_cast<ushort4*>(HI + a1) = h1;
        *reinterpret_cast<ushort4*>(LO + a1) = l1;
        acc += (double)v1.x * v1.x + (double)v1.y * v1.y +
               (double)v1.z * v1.z + (double)v1.w * v1.w;
    } else if (lane < 16) {                // zero K-pad: k = 300..319
        ushort4 z = {0, 0, 0, 0};
        int a1 = swaddr(rt, lr, (lane + 64) * 4);
        *reinterpret_cast<ushort4*>(HI + a1) = z;
        *reinterpret_cast<ushort4*>(LO + a1) = z;
    }
    for (int off = 32; off > 0; off >>= 1) acc += __shfl_down(acc, off, 64);
    if (lane == 0) {
        float rn = (float)(1.0 / sqrt(acc));   // norms ~17, eps unreachable
        if (isSen) {
            rsn[r] = rn;
            sflag[r] = (cat == none_idx[0]) ? 1 : 0;
        } else {
            ran[r] = rn;
        }
    }
}

// ---- sen_wd_emb: one wave per category, direct from emb ----
__global__ __launch_bounds__(64) void k_out2(const float* __restrict__ emb,
                                             const int* __restrict__ sen_cats,
                                             float* __restrict__ out2) {
    int b = blockIdx.x, lane = threadIdx.x;
    float4 s0 = make_float4(0.f, 0.f, 0.f, 0.f);
    float4 s1 = make_float4(0.f, 0.f, 0.f, 0.f);
#pragma unroll
    for (int w = 0; w < W; ++w) {          // w-ascending fp32 adds (ref order)
        int cat = sen_cats[b * W + w];
        const float4* src = reinterpret_cast<const float4*>(emb + (size_t)cat * D);
        float4 v0 = src[lane];
        s0.x += v0.x; s0.y += v0.y; s0.z += v0.z; s0.w += v0.w;
        if (lane < 11) {
            float4 v1 = src[lane + 64];
            s1.x += v1.x; s1.y += v1.y; s1.z += v1.z; s1.w += v1.w;
        }
    }
    float4* o = reinterpret_cast<float4*>(out2 + (size_t)b * D);
    o[lane] = s0;
    if (lane < 11) o[lane + 64] = s1;
}

// ---- main: EXACTLY round-8 (best measured): 4 waves, 64x64 wave tile ----
__global__ __launch_bounds__(256, 1) void k_main(const unsigned short* __restrict__ AHIu,
                                                 const unsigned short* __restrict__ ALOu,
                                                 const unsigned short* __restrict__ BHIu,
                                                 const unsigned short* __restrict__ BLOu,
                                                 const float* __restrict__ rsn,
                                                 const float* __restrict__ ran,
                                                 const int* __restrict__ sflag,
                                                 float* __restrict__ out) {
    const _Float16* AHI = reinterpret_cast<const _Float16*>(AHIu);
    const _Float16* ALO = reinterpret_cast<const _Float16*>(ALOu);
    const _Float16* BHI = reinterpret_cast<const _Float16*>(BHIu);
    const _Float16* BLO = reinterpret_cast<const _Float16*>(BLOu);

    __shared__ float cosld[128][128];   // 64 KB exactly

    int tid = threadIdx.x;
    int wv = tid >> 6, lane = tid & 63;
    int wy = wv >> 1, wx = wv & 1;      // wave's 64x64 quadrant
    int lr = lane & 15;
    int lk = lane >> 4;
    int by = blockIdx.y, bx = blockIdx.x;

    int aBase[4], bBase[4];
#pragma unroll
    for (int m = 0; m < 4; ++m)
        aBase[m] = (((by * 8 + wy * 4 + m) * NCHUNK) * 64 + lane) * 8;
#pragma unroll
    for (int n = 0; n < 4; ++n)
        bBase[n] = (((bx * 8 + wx * 4 + n) * NCHUNK) * 64 + lane) * 8;

    f32x4 acc[4][4] = {};
    half8 Ah[4], Al[4], Bh[4], Bl[4];

#pragma unroll
    for (int c = 0; c < NCHUNK; ++c) {
        int co = c * 512;
#pragma unroll
        for (int m = 0; m < 4; ++m) {
            Ah[m] = *reinterpret_cast<const half8*>(AHI + aBase[m] + co);
            Al[m] = *reinterpret_cast<const half8*>(ALO + aBase[m] + co);
        }
#pragma unroll
        for (int n = 0; n < 4; ++n) {
            Bh[n] = *reinterpret_cast<const half8*>(BHI + bBase[n] + co);
            Bl[n] = *reinterpret_cast<const half8*>(BLO + bBase[n] + co);
        }
#pragma unroll
        for (int m = 0; m < 4; ++m)
#pragma unroll
            for (int n = 0; n < 4; ++n) {
                acc[m][n] = __builtin_amdgcn_mfma_f32_16x16x32_f16(Ah[m], Bh[n], acc[m][n], 0, 0, 0);
                acc[m][n] = __builtin_amdgcn_mfma_f32_16x16x32_f16(Ah[m], Bl[n], acc[m][n], 0, 0, 0);
                acc[m][n] = __builtin_amdgcn_mfma_f32_16x16x32_f16(Al[m], Bh[n], acc[m][n], 0, 0, 0);
            }
    }

    // epilogue: cosine scale (C/D: col=lane&15, row=(lane>>4)*4+reg) -> LDS
#pragma unroll
    for (int m = 0; m < 4; ++m) {
        int rbase = wy * 64 + m * 16 + lk * 4;
#pragma unroll
        for (int r = 0; r < 4; ++r) {
            int grow = by * 128 + rbase + r;
            float rsv = rsn[grow];
            float fm = sflag[grow] ? 0.f : 1.f;
            float rf = rsv * fm;
#pragma unroll
            for (int n = 0; n < 4; ++n) {
                int lc = wx * 64 + n * 16 + lr;
                float rav = ran[bx * 128 + lc];
                cosld[rbase + r][lc] = acc[m][n][r] * rf * rav;
            }
        }
    }
    __syncthreads();

    // order-dependent fold: one (s,a) pair per thread, w-major order
    int pi = tid >> 4, pj = tid & 15;
    float cur = 0.f;
#pragma unroll
    for (int w = 0; w < W; ++w) {
        const float* rowp = &cosld[pi * 8 + w][pj * 8];
#pragma unroll
        for (int v = 0; v < W; ++v) {
            float sv = rowp[v];
            cur = (sv >= cur || sv < 0.f) ? sv : cur;
        }
    }
    out[(by * 16 + pi) * NA + (bx * 16 + pj)] = cur;
}

extern "C" void kernel_launch(void* const* d_in, const int* in_sizes, int n_in,
                              void* d_out, int out_size, void* d_ws, size_t ws_size,
                              hipStream_t stream) {
    const float* emb = (const float*)d_in[0];
    const int* sen = (const int*)d_in[1];
    const int* ann = (const int*)d_in[2];
    const int* none = (const int*)d_in[3];
    float* out = (float*)d_out;

    char* ws = (char*)d_ws;
    unsigned short* AHI = (unsigned short*)(ws + 0);         // 2048*320*2 = 1,310,720
    unsigned short* ALO = (unsigned short*)(ws + 1310720);
    unsigned short* BHI = (unsigned short*)(ws + 2621440);
    unsigned short* BLO = (unsigned short*)(ws + 3932160);
    float* rsn = (float*)(ws + 5242880);                     // 8,192
    float* ran = (float*)(ws + 5251072);                     // 8,192
    int* sflag = (int*)(ws + 5259264);                       // 8,192

    hipLaunchKernelGGL(k_gather, dim3(1024), dim3(256), 0, stream,
                       emb, sen, ann, none, AHI, ALO, BHI, BLO,
                       rsn, ran, sflag);
    hipLaunchKernelGGL(k_out2, dim3(NS), dim3(64), 0, stream,
                       emb, sen, out + NS * NA);
    hipLaunchKernelGGL(k_main, dim3(16, 16), dim3(256), 0, stream,
                       AHI, ALO, BHI, BLO, rsn, ran, sflag, out);
}

// Round 11
// 21.614 us; speedup vs baseline: 1.6746x; 1.4746x over previous
//
#include <hip/hip_runtime.h>
#include <hip/hip_fp16.h>

#define D 300
#define NS 256
#define NA 256
#define W 8
#define NROWS 2048    // 256*8
#define NCHUNK 10     // K padded to 10 chunks of 32 (320)

typedef _Float16 half8 __attribute__((ext_vector_type(8)));
typedef float f32x4 __attribute__((ext_vector_type(4)));

// Swizzled operand layout: [rt(128)][c(10)][lane(64)][e(8)] fp16
// lane = lk*16 + lr, where row = rt*16+lr, k = c*32 + lk*8 + e.
__device__ __forceinline__ int swaddr(int rt, int lr, int k4) {
    int c = k4 >> 5, lk = (k4 & 31) >> 3, e = k4 & 7;   // e in {0,4}
    return ((rt * NCHUNK + c) * 64 + lk * 16 + lr) * 8 + e;
}

__device__ __forceinline__ ushort4 cvt4(float4 v) {
    ushort4 h;
    h.x = __half_as_ushort(__float2half(v.x));
    h.y = __half_as_ushort(__float2half(v.y));
    h.z = __half_as_ushort(__float2half(v.z));
    h.w = __half_as_ushort(__float2half(v.w));
    return h;
}

// ---- gather: one wave per row, fp16 single (no hi/lo split) ----
__global__ __launch_bounds__(256) void k_gather(const float* __restrict__ emb,
                                                const int* __restrict__ sen_cats,
                                                const int* __restrict__ ann_cats,
                                                const int* __restrict__ none_idx,
                                                unsigned short* __restrict__ AH,
                                                unsigned short* __restrict__ BH,
                                                float* __restrict__ rsn,
                                                float* __restrict__ ran,
                                                int* __restrict__ sflag) {
    int tid = threadIdx.x;
    int wv = tid >> 6, lane = tid & 63;
    int task = blockIdx.x * 4 + wv;
    bool isSen = task < NROWS;
    int r = isSen ? task : task - NROWS;
    int cat = isSen ? sen_cats[r] : ann_cats[r];
    unsigned short* HI = isSen ? AH : BH;
    int rt = r >> 4, lr = r & 15;

    const float4* src = reinterpret_cast<const float4*>(emb + (size_t)cat * D);
    float4 v0 = src[lane];                 // indices 0..63 of 75
    *reinterpret_cast<ushort4*>(HI + swaddr(rt, lr, lane * 4)) = cvt4(v0);
    double acc = (double)v0.x * v0.x + (double)v0.y * v0.y +
                 (double)v0.z * v0.z + (double)v0.w * v0.w;
    if (lane < 11) {                       // indices 64..74
        float4 v1 = src[lane + 64];
        *reinterpret_cast<ushort4*>(HI + swaddr(rt, lr, (lane + 64) * 4)) = cvt4(v1);
        acc += (double)v1.x * v1.x + (double)v1.y * v1.y +
               (double)v1.z * v1.z + (double)v1.w * v1.w;
    } else if (lane < 16) {                // zero K-pad: k = 300..319
        ushort4 z = {0, 0, 0, 0};
        *reinterpret_cast<ushort4*>(HI + swaddr(rt, lr, (lane + 64) * 4)) = z;
    }
    for (int off = 32; off > 0; off >>= 1) acc += __shfl_down(acc, off, 64);
    if (lane == 0) {
        float rn = (float)(1.0 / sqrt(acc));   // norms ~17, eps unreachable
        if (isSen) {
            rsn[r] = rn;
            sflag[r] = (cat == none_idx[0]) ? 1 : 0;
        } else {
            ran[r] = rn;
        }
    }
}

// ---- sen_wd_emb: one block (2 waves) per category, lanes parallel over D ----
__global__ __launch_bounds__(128) void k_out2(const float* __restrict__ emb,
                                              const int* __restrict__ sen_cats,
                                              float* __restrict__ out2) {
    int b = blockIdx.x, i = threadIdx.x;
    if (i >= 75) return;
    float4 s = make_float4(0.f, 0.f, 0.f, 0.f);
#pragma unroll
    for (int w = 0; w < W; ++w) {          // w-ascending fp32 adds (ref order)
        int cat = sen_cats[b * W + w];
        float4 v = reinterpret_cast<const float4*>(emb + (size_t)cat * D)[i];
        s.x += v.x; s.y += v.y; s.z += v.z; s.w += v.w;
    }
    reinterpret_cast<float4*>(out2 + (size_t)b * D)[i] = s;
}

// ---- main: single-pass fp16 MFMA, swizzled contiguous operand loads ----
__global__ __launch_bounds__(256, 1) void k_main(const unsigned short* __restrict__ AHu,
                                                 const unsigned short* __restrict__ BHu,
                                                 const float* __restrict__ rsn,
                                                 const float* __restrict__ ran,
                                                 const int* __restrict__ sflag,
                                                 float* __restrict__ out) {
    const _Float16* AH = reinterpret_cast<const _Float16*>(AHu);
    const _Float16* BH = reinterpret_cast<const _Float16*>(BHu);

    __shared__ float cosld[128][128];   // 64 KB exactly

    int tid = threadIdx.x;
    int wv = tid >> 6, lane = tid & 63;
    int wy = wv >> 1, wx = wv & 1;      // wave's 64x64 quadrant
    int lr = lane & 15;
    int lk = lane >> 4;
    int by = blockIdx.y, bx = blockIdx.x;

    int aBase[4], bBase[4];
#pragma unroll
    for (int m = 0; m < 4; ++m)
        aBase[m] = (((by * 8 + wy * 4 + m) * NCHUNK) * 64 + lane) * 8;
#pragma unroll
    for (int n = 0; n < 4; ++n)
        bBase[n] = (((bx * 8 + wx * 4 + n) * NCHUNK) * 64 + lane) * 8;

    f32x4 acc[4][4] = {};
    half8 Ah[4], Bh[4];

#pragma unroll
    for (int c = 0; c < NCHUNK; ++c) {
        int co = c * 512;
#pragma unroll
        for (int m = 0; m < 4; ++m)
            Ah[m] = *reinterpret_cast<const half8*>(AH + aBase[m] + co);
#pragma unroll
        for (int n = 0; n < 4; ++n)
            Bh[n] = *reinterpret_cast<const half8*>(BH + bBase[n] + co);
#pragma unroll
        for (int m = 0; m < 4; ++m)
#pragma unroll
            for (int n = 0; n < 4; ++n)
                acc[m][n] = __builtin_amdgcn_mfma_f32_16x16x32_f16(Ah[m], Bh[n], acc[m][n], 0, 0, 0);
    }

    // epilogue: cosine scale (C/D: col=lane&15, row=(lane>>4)*4+reg) -> LDS
#pragma unroll
    for (int m = 0; m < 4; ++m) {
        int rbase = wy * 64 + m * 16 + lk * 4;
#pragma unroll
        for (int r = 0; r < 4; ++r) {
            int grow = by * 128 + rbase + r;
            float rsv = rsn[grow];
            float fm = sflag[grow] ? 0.f : 1.f;
            float rf = rsv * fm;
#pragma unroll
            for (int n = 0; n < 4; ++n) {
                int lc = wx * 64 + n * 16 + lr;
                float rav = ran[bx * 128 + lc];
                cosld[rbase + r][lc] = acc[m][n][r] * rf * rav;
            }
        }
    }
    __syncthreads();

    // order-dependent fold: one (s,a) pair per thread, w-major order
    int pi = tid >> 4, pj = tid & 15;
    float cur = 0.f;
#pragma unroll
    for (int w = 0; w < W; ++w) {
        const float* rowp = &cosld[pi * 8 + w][pj * 8];
#pragma unroll
        for (int v = 0; v < W; ++v) {
            float sv = rowp[v];
            cur = (sv >= cur || sv < 0.f) ? sv : cur;
        }
    }
    out[(by * 16 + pi) * NA + (bx * 16 + pj)] = cur;
}

extern "C" void kernel_launch(void* const* d_in, const int* in_sizes, int n_in,
                              void* d_out, int out_size, void* d_ws, size_t ws_size,
                              hipStream_t stream) {
    const float* emb = (const float*)d_in[0];
    const int* sen = (const int*)d_in[1];
    const int* ann = (const int*)d_in[2];
    const int* none = (const int*)d_in[3];
    float* out = (float*)d_out;

    char* ws = (char*)d_ws;
    unsigned short* AH = (unsigned short*)(ws + 0);          // 2048*320*2 = 1,310,720
    unsigned short* BH = (unsigned short*)(ws + 1310720);    // 1,310,720
    float* rsn = (float*)(ws + 2621440);                     // 8,192
    float* ran = (float*)(ws + 2629632);                     // 8,192
    int* sflag = (int*)(ws + 2637824);                       // 8,192

    hipLaunchKernelGGL(k_gather, dim3(1024), dim3(256), 0, stream,
                       emb, sen, ann, none, AH, BH, rsn, ran, sflag);
    hipLaunchKernelGGL(k_out2, dim3(NS), dim3(128), 0, stream,
                       emb, sen, out + NS * NA);
    hipLaunchKernelGGL(k_main, dim3(16, 16), dim3(256), 0, stream,
                       AH, BH, rsn, ran, sflag, out);
}